// Round 7
// baseline (227.756 us; speedup 1.0000x reference)
//
#include <hip/hip_runtime.h>
#include <math.h>
#include <stdint.h>

constexpr int NN = 50000;   // nodes
constexpr int EE = 800000;  // edges
constexpr int D  = 128;     // feature dim
constexpr int KK = 512;     // effective GEMM K (t folded into r)
constexpr int BM = 64;      // gemm row tile -> 782 blocks (~3/CU)
constexpr int BK = 64;      // gemm k tile
constexpr int NPAD = 50048; // 782 * 64
constexpr int CAP = 64;     // per-node edge bucket capacity (deg ~ Poisson(12))

typedef __attribute__((ext_vector_type(8)))  short bf16x8;
typedef __attribute__((ext_vector_type(16))) float f32x16;

__device__ inline unsigned short f2bf(float x) {
    unsigned u = __builtin_bit_cast(unsigned, x);
    unsigned r = (u + 0x7FFF + ((u >> 16) & 1)) >> 16;   // RNE
    return (unsigned short)r;
}
__device__ inline float bf2f(unsigned short b) {
    unsigned u = ((unsigned)b) << 16;
    return __builtin_bit_cast(float, u);
}

// ---------------------------------------------------------------------------
// h f32 -> Xfull[n][0:128) bf16 (identical rounding to what gemm staging did).
// ---------------------------------------------------------------------------
__global__ __launch_bounds__(256) void h2bf16(const float* __restrict__ h,
                                              unsigned short* __restrict__ Xfull)
{
    int idx = blockIdx.x * 256 + threadIdx.x;   // NN*16 threads, 8 elems each
    int n  = idx >> 4;
    int c8 = (idx & 15) * 8;
    const float* hp = h + (size_t)n * D + c8;
    float4 f0 = *(const float4*)hp;
    float4 f1 = *(const float4*)(hp + 4);
    float ff[8] = {f0.x, f0.y, f0.z, f0.w, f1.x, f1.y, f1.z, f1.w};
    short b8[8];
#pragma unroll
    for (int j = 0; j < 8; ++j) b8[j] = (short)f2bf(ff[j]);
    *(bf16x8*)(Xfull + (size_t)n * KK + c8) = *(bf16x8*)b8;
}

// ---------------------------------------------------------------------------
// W[128][640] -> Wfh/Wfl in MFMA B-fragment order, t-block folded into r.
// Wf[((cb*64 + ksl)*32 + ln)*8 + j] = W_eff[cb*32+ln][ksl*8+j]  (hi / lo)
// ---------------------------------------------------------------------------
__global__ __launch_bounds__(256) void prep_wfrag(const float* __restrict__ W,
                                                  unsigned short* __restrict__ Wfh,
                                                  unsigned short* __restrict__ Wfl)
{
    int tid = blockIdx.x * 256 + threadIdx.x;  // 8192 = 4cb * 64ksl * 32ln
    int ln  = tid & 31;
    int ksl = (tid >> 5) & 63;
    int cb  = tid >> 11;
    int col = cb * 32 + ln;
    short h8[8], l8[8];
#pragma unroll
    for (int j = 0; j < 8; ++j) {
        int k = ksl * 8 + j;
        float v = W[col * 640 + k];
        if (k >= 128 && k < 256) v += W[col * 640 + k + 384];
        unsigned short hb = f2bf(v);
        h8[j] = (short)hb;
        l8[j] = (short)f2bf(v - bf2f(hb));
    }
    *(bf16x8*)(Wfh + (size_t)tid * 8) = *(bf16x8*)h8;
    *(bf16x8*)(Wfl + (size_t)tid * 8) = *(bf16x8*)l8;
}

// ---------------------------------------------------------------------------
// Single-kernel edge binning into fixed-capacity buckets. deg zeroed first.
// p==3 edges dropped.
// ---------------------------------------------------------------------------
__global__ __launch_bounds__(256) void fill_bucket(const int* __restrict__ src,
                                                   const int* __restrict__ dst,
                                                   const int* __restrict__ pos,
                                                   const float* __restrict__ dist,
                                                   int* __restrict__ deg,
                                                   int2* __restrict__ bucket)
{
    int e = blockIdx.x * 256 + threadIdx.x;
    if (e >= EE) return;
    int p = pos[e];
    if (p == 3) return;
    int d_ = dst[e];
    int slot = atomicAdd(&deg[d_], 1);
    if (slot < CAP)
        bucket[(size_t)d_ * CAP + slot] =
            make_int2(src[e] | (p << 16), __float_as_int(dist[e]));
}

// ---------------------------------------------------------------------------
// Gather-aggregation: one wave per dst node, 2 edges per step via half-waves
// (lanes 0-31 = edge 2j, lanes 32-63 = edge 2j+1; 16B float4 per lane =
// 4 cols/lane). Every chunk is predicated-8-deep -- NO serial tail. Halves
// combined with one shfl_xor(32). Output bf16 to Xfull[node][128:512).
// ---------------------------------------------------------------------------
__global__ __launch_bounds__(256) void gather_agg(const float* __restrict__ h,
                                                  const int2* __restrict__ bucket,
                                                  const int* __restrict__ deg,
                                                  unsigned short* __restrict__ Xfull)
{
    int node = (blockIdx.x * 256 + threadIdx.x) >> 6;
    if (node >= NN) return;
    int lane = threadIdx.x & 63;
    int hs = lane >> 5;            // half-wave index
    int c0 = (lane & 31) * 4;      // this lane's 4 columns
    int n = deg[node];
    if (n > CAP) n = CAP;

    int2 mreg = (lane < n) ? bucket[(size_t)node * CAP + lane] : make_int2(0, 0);

    float a0[4] = {0.f, 0.f, 0.f, 0.f};
    float a1[4] = {0.f, 0.f, 0.f, 0.f};
    float a2[4] = {0.f, 0.f, 0.f, 0.f};

    for (int base = 0; base < n; base += 16) {    // 16 edges per round
        float4 v[8];
        float  wq[8];
        int    pq[8];
#pragma unroll
        for (int j = 0; j < 8; ++j) {
            int idx = base + 2 * j + hs;
            bool pred = idx < n;
            int mx = __shfl(mreg.x, idx & 63, 64);
            int my = __shfl(mreg.y, idx & 63, 64);
            pq[j] = mx >> 16;
            wq[j] = pred ? __int_as_float(my) : 0.f;
            const float* hp = h + (size_t)(mx & 0xFFFF) * D + c0;
            v[j] = pred ? *(const float4*)hp : make_float4(0.f, 0.f, 0.f, 0.f);
        }
#pragma unroll
        for (int j = 0; j < 8; ++j) {
            float w0 = (pq[j] == 0) ? wq[j] : 0.f;
            float w1 = (pq[j] == 1) ? wq[j] : 0.f;
            float w2 = (pq[j] == 2) ? wq[j] : 0.f;
            float vv[4] = {v[j].x, v[j].y, v[j].z, v[j].w};
#pragma unroll
            for (int c = 0; c < 4; ++c) {
                a0[c] = fmaf(vv[c], w0, a0[c]);
                a1[c] = fmaf(vv[c], w1, a1[c]);
                a2[c] = fmaf(vv[c], w2, a2[c]);
            }
        }
    }

    // combine the two half-waves (lane i and i+32 hold the same columns)
#pragma unroll
    for (int c = 0; c < 4; ++c) {
        a0[c] += __shfl_xor(a0[c], 32, 64);
        a1[c] += __shfl_xor(a1[c], 32, 64);
        a2[c] += __shfl_xor(a2[c], 32, 64);
    }

    // write: lanes 0-31 emit segments p0,p1; lanes 32-63 emit p2
    size_t rowb = (size_t)node * KK;
    if (hs == 0) {
        uint2 w0 = make_uint2((unsigned)f2bf(a0[0]) | ((unsigned)f2bf(a0[1]) << 16),
                              (unsigned)f2bf(a0[2]) | ((unsigned)f2bf(a0[3]) << 16));
        uint2 w1 = make_uint2((unsigned)f2bf(a1[0]) | ((unsigned)f2bf(a1[1]) << 16),
                              (unsigned)f2bf(a1[2]) | ((unsigned)f2bf(a1[3]) << 16));
        *(uint2*)(Xfull + rowb + 128 + c0) = w0;
        *(uint2*)(Xfull + rowb + 256 + c0) = w1;
    } else {
        uint2 w2 = make_uint2((unsigned)f2bf(a2[0]) | ((unsigned)f2bf(a2[1]) << 16),
                              (unsigned)f2bf(a2[2]) | ((unsigned)f2bf(a2[3]) << 16));
        *(uint2*)(Xfull + rowb + 384 + c0) = w2;
    }
}

// ---------------------------------------------------------------------------
// MFMA GEMM (M=NPAD, N=128, K=512), X bf16-hi, W hi+lo (2 MFMA terms).
// BM=64 -> 782 blocks (~3/CU). 4 waves (2 row x 2 col), wave = 32 rows x 64 cols.
// A: uniform Xfull loads, global->reg->LDS double-buffered 2x8KB, XOR swizzle.
// B: direct global->VGPR fragment loads from pre-swizzled Wfh/Wfl (L2-resident).
// C layout: col=lane&31, row=(reg&3)+8*(reg>>2)+4*(lane>>5).
// ---------------------------------------------------------------------------
__global__ __launch_bounds__(256, 3) void gemm_mfma(
    const unsigned short* __restrict__ Xfull,
    const unsigned short* __restrict__ Wfh, const unsigned short* __restrict__ Wfl,
    const float* __restrict__ bias, const float* __restrict__ gamma,
    const float* __restrict__ beta, float* __restrict__ out)
{
    __shared__ __align__(16) short lds[2 * BM * BK];   // 16 KB (2 bufs)

    const int t = threadIdx.x;
    const int l = t & 63;
    const int w = t >> 6;
    const int wr = (w & 1) * 32;       // wave row base
    const int wch = (w >> 1);          // wave col half: cols wch*64 .. +63
    const int row0 = blockIdx.x * BM;
    const int ln = l & 31;
    const int hs = l >> 5;

    // A staging coords: 2 chunks of 16B per thread per tile
    int crow[2], cks[2], clof[2];
#pragma unroll
    for (int p = 0; p < 2; ++p) {
        int idx = t + 256 * p;             // 0..511
        crow[p] = idx >> 3;                // 0..63
        cks[p]  = idx & 7;
        clof[p] = crow[p] * 64 + ((cks[p] ^ (crow[p] & 7)) * 8);
    }

    float4 pa[2];                          // A prefetch regs

    auto LOADA = [&](int kt) {
        const int k0 = kt * BK;
#pragma unroll
        for (int p = 0; p < 2; ++p) {
            size_t ga = (size_t)(row0 + crow[p]) * KK + k0 + cks[p] * 8;
            pa[p] = *(const float4*)(Xfull + ga);
        }
    };
    auto STOREA = [&](short* buf) {
#pragma unroll
        for (int p = 0; p < 2; ++p)
            *(float4*)(buf + clof[p]) = pa[p];
    };

    f32x16 acc[2];
#pragma unroll
    for (int cb = 0; cb < 2; ++cb)
#pragma unroll
        for (int i = 0; i < 16; ++i) acc[cb][i] = 0.f;

    LOADA(0);
    STOREA(lds);
    LOADA(1);
    __syncthreads();

    for (int kt = 0; kt < 8; ++kt) {
        short* buf = lds + (kt & 1) * BM * BK;
        // B fragments for this tile: direct global loads (L2), coalesced
        bf16x8 bfh[2][4], bfl[2][4];
#pragma unroll
        for (int cb = 0; cb < 2; ++cb)
#pragma unroll
            for (int kk = 0; kk < 4; ++kk) {
                size_t fo = ((size_t)((wch * 2 + cb) * 64 + kt * 8 + kk * 2 + hs)
                             * 32 + ln) * 8;
                bfh[cb][kk] = *(const bf16x8*)(Wfh + fo);
                bfl[cb][kk] = *(const bf16x8*)(Wfl + fo);
            }
        if (kt < 7) STOREA(lds + ((kt + 1) & 1) * BM * BK);
        if (kt < 6) LOADA(kt + 2);

        __builtin_amdgcn_s_setprio(1);
#pragma unroll
        for (int kk = 0; kk < 4; ++kk) {
            int ksl = kk * 2 + hs;
            int row = wr + ln;
            bf16x8 a = *(const bf16x8*)(buf + row * 64 + ((ksl ^ (row & 7)) * 8));
#pragma unroll
            for (int cb = 0; cb < 2; ++cb) {
                acc[cb] = __builtin_amdgcn_mfma_f32_32x32x16_bf16(
                    a, bfh[cb][kk], acc[cb], 0, 0, 0);
                acc[cb] = __builtin_amdgcn_mfma_f32_32x32x16_bf16(
                    a, bfl[cb][kk], acc[cb], 0, 0, 0);
            }
        }
        __builtin_amdgcn_s_setprio(0);
        __syncthreads();                   // buf readers done; next STOREA safe
    }

    // ---- fused bias + LayerNorm + ReLU epilogue ----
    float* part = (float*)lds;             // [2 col-half][64 row][2] f32 = 1KB
    float bias_c[2] = {bias[wch * 64 + ln], bias[wch * 64 + 32 + ln]};

#pragma unroll
    for (int reg = 0; reg < 16; ++reg) {
        float z0 = acc[0][reg] + bias_c[0];
        float z1 = acc[1][reg] + bias_c[1];
        acc[0][reg] = z0;
        acc[1][reg] = z1;
        float s = z0 + z1, ss = z0 * z0 + z1 * z1;
#pragma unroll
        for (int m = 1; m < 32; m <<= 1) {     // stays within 32-lane half
            s  += __shfl_xor(s, m, 64);
            ss += __shfl_xor(ss, m, 64);
        }
        int rl = wr + (reg & 3) + 8 * (reg >> 2) + 4 * hs;
        if (ln == 0) {
            part[wch * 128 + rl * 2]     = s;
            part[wch * 128 + rl * 2 + 1] = ss;
        }
    }
    __syncthreads();

    float g_c[2]  = {gamma[wch * 64 + ln], gamma[wch * 64 + 32 + ln]};
    float be_c[2] = {beta[wch * 64 + ln],  beta[wch * 64 + 32 + ln]};
#pragma unroll
    for (int reg = 0; reg < 16; ++reg) {
        int rl = wr + (reg & 3) + 8 * (reg >> 2) + 4 * hs;
        float s  = part[rl * 2]     + part[128 + rl * 2];
        float ss = part[rl * 2 + 1] + part[128 + rl * 2 + 1];
        float mu  = s * (1.f / 128.f);
        float var = ss * (1.f / 128.f) - mu * mu;
        float rs  = rsqrtf(var + 1e-5f);
        int grow = row0 + rl;
        if (grow < NN) {
            float v0 = (acc[0][reg] - mu) * rs * g_c[0] + be_c[0];
            float v1 = (acc[1][reg] - mu) * rs * g_c[1] + be_c[1];
            out[(size_t)grow * D + wch * 64 + ln]      = v0 > 0.f ? v0 : 0.f;
            out[(size_t)grow * D + wch * 64 + 32 + ln] = v1 > 0.f ? v1 : 0.f;
        }
    }
}

// ---------------------------------------------------------------------------
extern "C" void kernel_launch(void* const* d_in, const int* in_sizes, int n_in,
                              void* d_out, int out_size, void* d_ws, size_t ws_size,
                              hipStream_t stream)
{
    const float* h     = (const float*)d_in[0];
    const float* dist  = (const float*)d_in[1];
    const float* W     = (const float*)d_in[2];
    const float* bias  = (const float*)d_in[3];
    const float* gamma = (const float*)d_in[4];
    const float* beta  = (const float*)d_in[5];
    const int*   src   = (const int*)d_in[6];
    const int*   dst   = (const int*)d_in[7];
    const int*   pos   = (const int*)d_in[8];

    // workspace layout
    unsigned short* Xfull = (unsigned short*)d_ws;          // [NPAD][512] bf16
    unsigned short* Wfh = Xfull + (size_t)NPAD * KK;        // 128KB frag-order
    unsigned short* Wfl = Wfh + 128 * KK;                   // 128KB frag-order
    int*  deg    = (int*)(Wfl + 128 * KK);                  // [NN]
    int2* bucket = (int2*)(((uintptr_t)(deg + NN) + 15) & ~(uintptr_t)15);

    hipMemsetAsync(deg, 0, NN * sizeof(int), stream);

    h2bf16<<<(NN * 16) / 256, 256, 0, stream>>>(h, Xfull);
    prep_wfrag<<<32, 256, 0, stream>>>(W, Wfh, Wfl);
    fill_bucket<<<(EE + 255) / 256, 256, 0, stream>>>(src, dst, pos, dist, deg, bucket);
    gather_agg<<<(NN * 64) / 256, 256, 0, stream>>>(h, bucket, deg, Xfull);
    gemm_mfma<<<NPAD / BM, 256, 0, stream>>>(Xfull, Wfh, Wfl, bias, gamma,
                                             beta, (float*)d_out);
}

// Round 8
// 199.184 us; speedup vs baseline: 1.1434x; 1.1434x over previous
//
#include <hip/hip_runtime.h>
#include <math.h>
#include <stdint.h>

constexpr int NN = 50000;   // nodes
constexpr int EE = 800000;  // edges
constexpr int D  = 128;     // feature dim
constexpr int KK = 512;     // effective GEMM K (t folded into r)
constexpr int BM = 32;      // fused block rows -> 1563 blocks (~6/CU)
constexpr int CAP = 64;     // per-node edge bucket capacity (deg ~ Poisson(12))
constexpr int NBLK = (NN + BM - 1) / BM;   // 1563

typedef __attribute__((ext_vector_type(8)))  short bf16x8;
typedef __attribute__((ext_vector_type(16))) float f32x16;

__device__ inline unsigned short f2bf(float x) {
    unsigned u = __builtin_bit_cast(unsigned, x);
    unsigned r = (u + 0x7FFF + ((u >> 16) & 1)) >> 16;   // RNE
    return (unsigned short)r;
}
__device__ inline float bf2f(unsigned short b) {
    unsigned u = ((unsigned)b) << 16;
    return __builtin_bit_cast(float, u);
}

// ---------------------------------------------------------------------------
// W[128][640] -> Wfh/Wfl in MFMA B-fragment order, t-block folded into r.
// Wf[((cb*64 + slot)*32 + ln)*8 + j] = W_eff[cb*32+ln][slot*8+j]  (hi / lo)
// cb = wave's 32-col block. One coalesced dwordx4 per B-frag in the GEMM.
// ---------------------------------------------------------------------------
__global__ __launch_bounds__(256) void prep_wfrag(const float* __restrict__ W,
                                                  unsigned short* __restrict__ Wfh,
                                                  unsigned short* __restrict__ Wfl)
{
    int tid = blockIdx.x * 256 + threadIdx.x;  // 8192 = 4cb * 64slot * 32ln
    int ln  = tid & 31;
    int slot = (tid >> 5) & 63;
    int cb  = tid >> 11;
    int col = cb * 32 + ln;
    short h8[8], l8[8];
#pragma unroll
    for (int j = 0; j < 8; ++j) {
        int k = slot * 8 + j;
        float v = W[col * 640 + k];
        if (k >= 128 && k < 256) v += W[col * 640 + k + 384];
        unsigned short hb = f2bf(v);
        h8[j] = (short)hb;
        l8[j] = (short)f2bf(v - bf2f(hb));
    }
    *(bf16x8*)(Wfh + (size_t)tid * 8) = *(bf16x8*)h8;
    *(bf16x8*)(Wfl + (size_t)tid * 8) = *(bf16x8*)l8;
}

// ---------------------------------------------------------------------------
// Single-kernel edge binning into fixed-capacity buckets. deg zeroed first.
// p==3 edges dropped.
// ---------------------------------------------------------------------------
__global__ __launch_bounds__(256) void fill_bucket(const int* __restrict__ src,
                                                   const int* __restrict__ dst,
                                                   const int* __restrict__ pos,
                                                   const float* __restrict__ dist,
                                                   int* __restrict__ deg,
                                                   int2* __restrict__ bucket)
{
    int e = blockIdx.x * 256 + threadIdx.x;
    if (e >= EE) return;
    int p = pos[e];
    if (p == 3) return;
    int d_ = dst[e];
    int slot = atomicAdd(&deg[d_], 1);
    if (slot < CAP)
        bucket[(size_t)d_ * CAP + slot] =
            make_int2(src[e] | (p << 16), __float_as_int(dist[e]));
}

// ---------------------------------------------------------------------------
// FUSED: h-stage + gather-aggregate + MFMA GEMM (K=512) + bias + LN + ReLU.
// Block = 32 output rows, 256 threads (4 waves).
// LDS A-tile Af: 64 slots x 32 rows x 8 bf16 (32 KB), swizzled
//   addr16(s,row) = s*32 + (row ^ (s & 31))   [16B units]
// -> conflict-free for gather writes AND MFMA fragment reads (verified mod-32).
// Phase A: slots 0..15 from h (f32->bf16). Phase B: slots 16..63 from gather.
// Phase C: per wave 64 MFMAs (32 k-steps x W hi/lo), B direct from L2 frags,
// NO barriers inside the k-loop. Phase D: cross-wave LN via LDS partials.
// C frag layout: col=lane&31, row=(reg&3)+8*(reg>>2)+4*(lane>>5).
// ---------------------------------------------------------------------------
__global__ __launch_bounds__(256, 4) void fused_agg_gemm(
    const float* __restrict__ h,
    const int2* __restrict__ bucket, const int* __restrict__ deg,
    const unsigned short* __restrict__ Wfh, const unsigned short* __restrict__ Wfl,
    const float* __restrict__ bias, const float* __restrict__ gamma,
    const float* __restrict__ beta, float* __restrict__ out)
{
    __shared__ __align__(16) short Af[64 * 32 * 8];   // 32 KB

    const int t = threadIdx.x;
    const int lane = t & 63;
    const int w = t >> 6;
    const int ln = lane & 31;
    const int hs = lane >> 5;
    const int node0 = blockIdx.x * BM;

    // ---- Phase A: h rows -> Af slots 0..15 (k = 0..127) ----
    {
        int row = t >> 3;          // 0..31
        int g   = t & 7;           // col group: cols 16g..16g+15
        int node = node0 + row;
        float ff[16];
        if (node < NN) {
            const float* hp = h + (size_t)node * D + g * 16;
            float4 f0 = *(const float4*)hp;
            float4 f1 = *(const float4*)(hp + 4);
            float4 f2 = *(const float4*)(hp + 8);
            float4 f3 = *(const float4*)(hp + 12);
            ff[0]=f0.x; ff[1]=f0.y; ff[2]=f0.z; ff[3]=f0.w;
            ff[4]=f1.x; ff[5]=f1.y; ff[6]=f1.z; ff[7]=f1.w;
            ff[8]=f2.x; ff[9]=f2.y; ff[10]=f2.z; ff[11]=f2.w;
            ff[12]=f3.x; ff[13]=f3.y; ff[14]=f3.z; ff[15]=f3.w;
        } else {
#pragma unroll
            for (int j = 0; j < 16; ++j) ff[j] = 0.f;
        }
        short b16[16];
#pragma unroll
        for (int j = 0; j < 16; ++j) b16[j] = (short)f2bf(ff[j]);
        int s0 = 2 * g, s1 = 2 * g + 1;
        *(bf16x8*)(Af + (s0 * 32 + (row ^ s0)) * 8) = *(bf16x8*)&b16[0];
        *(bf16x8*)(Af + (s1 * 32 + (row ^ s1)) * 8) = *(bf16x8*)&b16[8];
    }

    // ---- Phase B: gather-aggregate 8 nodes per wave -> Af slots 16..63 ----
    const int c0 = ln * 4;         // this lane's 4 columns (per half-wave)
    for (int i = 0; i < 8; ++i) {
        int r = w * 8 + i;         // row within tile
        int node = node0 + r;
        int n = 0;
        if (node < NN) {
            n = deg[node];
            if (n > CAP) n = CAP;
        }
        int2 mreg = (lane < n) ? bucket[(size_t)node * CAP + lane]
                               : make_int2(0, 0);

        float a0[4] = {0.f, 0.f, 0.f, 0.f};
        float a1[4] = {0.f, 0.f, 0.f, 0.f};
        float a2[4] = {0.f, 0.f, 0.f, 0.f};

        for (int base = 0; base < n; base += 16) {   // 16 edges per round
            float4 v[8];
            float  wq[8];
            int    pq[8];
#pragma unroll
            for (int j = 0; j < 8; ++j) {
                int idx = base + 2 * j + hs;
                bool pred = idx < n;
                int mx = __shfl(mreg.x, idx & 63, 64);
                int my = __shfl(mreg.y, idx & 63, 64);
                pq[j] = mx >> 16;
                wq[j] = pred ? __int_as_float(my) : 0.f;
                const float* hp = h + (size_t)(mx & 0xFFFF) * D + c0;
                v[j] = pred ? *(const float4*)hp : make_float4(0.f,0.f,0.f,0.f);
            }
#pragma unroll
            for (int j = 0; j < 8; ++j) {
                float w0 = (pq[j] == 0) ? wq[j] : 0.f;
                float w1 = (pq[j] == 1) ? wq[j] : 0.f;
                float w2 = (pq[j] == 2) ? wq[j] : 0.f;
                float vv[4] = {v[j].x, v[j].y, v[j].z, v[j].w};
#pragma unroll
                for (int c = 0; c < 4; ++c) {
                    a0[c] = fmaf(vv[c], w0, a0[c]);
                    a1[c] = fmaf(vv[c], w1, a1[c]);
                    a2[c] = fmaf(vv[c], w2, a2[c]);
                }
            }
        }
        // combine half-waves (lane l and l+32 hold the same columns)
#pragma unroll
        for (int c = 0; c < 4; ++c) {
            a0[c] += __shfl_xor(a0[c], 32, 64);
            a1[c] += __shfl_xor(a1[c], 32, 64);
            a2[c] += __shfl_xor(a2[c], 32, 64);
        }
        // write: lanes 0-31 emit segments p0 (slots 16..31), p1 (32..47);
        //        lanes 32-63 emit p2 (slots 48..63). 8B per lane per segment.
        int sb = ln >> 1;
        int bo = (ln & 1) * 4;     // short offset inside the 16B slot
        if (hs == 0) {
            uint2 u0 = make_uint2((unsigned)f2bf(a0[0]) | ((unsigned)f2bf(a0[1]) << 16),
                                  (unsigned)f2bf(a0[2]) | ((unsigned)f2bf(a0[3]) << 16));
            uint2 u1 = make_uint2((unsigned)f2bf(a1[0]) | ((unsigned)f2bf(a1[1]) << 16),
                                  (unsigned)f2bf(a1[2]) | ((unsigned)f2bf(a1[3]) << 16));
            int s = 16 + sb;
            *(uint2*)(Af + (s * 32 + (r ^ (s & 31))) * 8 + bo) = u0;
            s = 32 + sb;
            *(uint2*)(Af + (s * 32 + (r ^ (s & 31))) * 8 + bo) = u1;
        } else {
            uint2 u2 = make_uint2((unsigned)f2bf(a2[0]) | ((unsigned)f2bf(a2[1]) << 16),
                                  (unsigned)f2bf(a2[2]) | ((unsigned)f2bf(a2[3]) << 16));
            int s = 48 + sb;
            *(uint2*)(Af + (s * 32 + (r ^ (s & 31))) * 8 + bo) = u2;
        }
    }

    __syncthreads();   // A-tile complete

    // ---- Phase C: GEMM, K=512, no inner barriers ----
    f32x16 acc;
#pragma unroll
    for (int i = 0; i < 16; ++i) acc[i] = 0.f;

    auto LOADB = [&](int k16, bf16x8& bh, bf16x8& bl) {
        size_t fo = ((size_t)(w * 64 + k16 * 2 + hs) * 32 + ln) * 8;
        bh = *(const bf16x8*)(Wfh + fo);
        bl = *(const bf16x8*)(Wfl + fo);
    };
    auto LOADA = [&](int k16) -> bf16x8 {
        int s = k16 * 2 + hs;
        return *(const bf16x8*)(Af + (s * 32 + (ln ^ (s & 31))) * 8);
    };

    bf16x8 bh0, bl0, bh1, bl1;
    LOADB(0, bh0, bl0);
#pragma unroll
    for (int k16 = 0; k16 < 32; k16 += 2) {
        if (k16 + 1 < 32) LOADB(k16 + 1, bh1, bl1);
        bf16x8 aa = LOADA(k16);
        __builtin_amdgcn_s_setprio(1);
        acc = __builtin_amdgcn_mfma_f32_32x32x16_bf16(aa, bh0, acc, 0, 0, 0);
        acc = __builtin_amdgcn_mfma_f32_32x32x16_bf16(aa, bl0, acc, 0, 0, 0);
        __builtin_amdgcn_s_setprio(0);
        if (k16 + 2 < 32) LOADB(k16 + 2, bh0, bl0);
        aa = LOADA(k16 + 1);
        __builtin_amdgcn_s_setprio(1);
        acc = __builtin_amdgcn_mfma_f32_32x32x16_bf16(aa, bh1, acc, 0, 0, 0);
        acc = __builtin_amdgcn_mfma_f32_32x32x16_bf16(aa, bl1, acc, 0, 0, 0);
        __builtin_amdgcn_s_setprio(0);
    }

    __syncthreads();   // Af reads done; reuse LDS for LN partials

    // ---- Phase D: bias + LayerNorm + ReLU ----
    float* part = (float*)Af;              // [4 wave][32 row][2] f32 = 1 KB
    float bias_c = bias[w * 32 + ln];

#pragma unroll
    for (int reg = 0; reg < 16; ++reg) {
        float z = acc[reg] + bias_c;
        acc[reg] = z;
        float s = z, ss = z * z;
#pragma unroll
        for (int m = 1; m < 32; m <<= 1) {     // stays within 32-lane half
            s  += __shfl_xor(s, m, 64);
            ss += __shfl_xor(ss, m, 64);
        }
        int rl = (reg & 3) + 8 * (reg >> 2) + 4 * hs;
        if (ln == 0) {
            part[(w * 32 + rl) * 2]     = s;
            part[(w * 32 + rl) * 2 + 1] = ss;
        }
    }
    __syncthreads();

    float g_c  = gamma[w * 32 + ln];
    float be_c = beta[w * 32 + ln];
#pragma unroll
    for (int reg = 0; reg < 16; ++reg) {
        int rl = (reg & 3) + 8 * (reg >> 2) + 4 * hs;
        float s  = part[rl * 2]     + part[(32 + rl) * 2]
                 + part[(64 + rl) * 2] + part[(96 + rl) * 2];
        float ss = part[rl * 2 + 1] + part[(32 + rl) * 2 + 1]
                 + part[(64 + rl) * 2 + 1] + part[(96 + rl) * 2 + 1];
        float mu  = s * (1.f / 128.f);
        float var = ss * (1.f / 128.f) - mu * mu;
        float rs  = rsqrtf(var + 1e-5f);
        int grow = node0 + rl;
        if (grow < NN) {
            float v = (acc[reg] - mu) * rs * g_c + be_c;
            out[(size_t)grow * D + w * 32 + ln] = v > 0.f ? v : 0.f;
        }
    }
}

// ---------------------------------------------------------------------------
extern "C" void kernel_launch(void* const* d_in, const int* in_sizes, int n_in,
                              void* d_out, int out_size, void* d_ws, size_t ws_size,
                              hipStream_t stream)
{
    const float* h     = (const float*)d_in[0];
    const float* dist  = (const float*)d_in[1];
    const float* W     = (const float*)d_in[2];
    const float* bias  = (const float*)d_in[3];
    const float* gamma = (const float*)d_in[4];
    const float* beta  = (const float*)d_in[5];
    const int*   src   = (const int*)d_in[6];
    const int*   dst   = (const int*)d_in[7];
    const int*   pos   = (const int*)d_in[8];

    // workspace layout
    unsigned short* Wfh = (unsigned short*)d_ws;            // 128KB frag-order
    unsigned short* Wfl = Wfh + 128 * KK;                   // 128KB frag-order
    int*  deg    = (int*)(Wfl + 128 * KK);                  // [NN]
    int2* bucket = (int2*)(((uintptr_t)(deg + NN) + 15) & ~(uintptr_t)15);

    hipMemsetAsync(deg, 0, NN * sizeof(int), stream);

    prep_wfrag<<<32, 256, 0, stream>>>(W, Wfh, Wfl);
    fill_bucket<<<(EE + 255) / 256, 256, 0, stream>>>(src, dst, pos, dist, deg, bucket);
    fused_agg_gemm<<<NBLK, 256, 0, stream>>>(h, bucket, deg, Wfh, Wfl,
                                             bias, gamma, beta, (float*)d_out);
}

// Round 9
// 190.883 us; speedup vs baseline: 1.1932x; 1.0435x over previous
//
#include <hip/hip_runtime.h>
#include <math.h>
#include <stdint.h>

constexpr int NN = 50000;   // nodes
constexpr int EE = 800000;  // edges
constexpr int D  = 128;     // feature dim
constexpr int CAP = 64;     // per-node bucket capacity (deg ~ Poisson(12))
constexpr int BM = 32;      // pre-GEMM row tile
constexpr int NBX = (NN + BM - 1) / BM;   // 1563

typedef __attribute__((ext_vector_type(8)))  short bf16x8;
typedef __attribute__((ext_vector_type(16))) float f32x16;

__device__ inline unsigned short f2bf(float x) {
    unsigned u = __builtin_bit_cast(unsigned, x);
    unsigned r = (u + 0x7FFF + ((u >> 16) & 1)) >> 16;   // RNE
    return (unsigned short)r;
}
__device__ inline float bf2f(unsigned short b) {
    unsigned u = ((unsigned)b) << 16;
    return __builtin_bit_cast(float, u);
}

// ---------------------------------------------------------------------------
// W[128][640] -> Wfh/Wfl bf16 hi/lo in MFMA B-fragment order over 512 virtual
// out-cols (vc): vc 0-127 = W0 (h), 128-255 = W1+W4 (p0, t folded),
// 256-383 = W2 (p1), 384-511 = W3 (p2). K = 128 (h dim).
// Wf[(((vcb*8 + s)*2 + hs)*32 + ln)*8 + j] = W_eff[vcb*32+ln][s*16+hs*8+j]
// ---------------------------------------------------------------------------
__global__ __launch_bounds__(256) void prep_wfrag(const float* __restrict__ W,
                                                  unsigned short* __restrict__ Wfh,
                                                  unsigned short* __restrict__ Wfl)
{
    int tid = blockIdx.x * 256 + threadIdx.x;  // 8192 = 16vcb * 8s * 2hs * 32ln
    int ln  = tid & 31;
    int hs  = (tid >> 5) & 1;
    int s   = (tid >> 6) & 7;
    int vcb = tid >> 9;
    int oc  = vcb * 32 + ln;                   // virtual out-col
    short h8[8], l8[8];
#pragma unroll
    for (int j = 0; j < 8; ++j) {
        int k = s * 16 + hs * 8 + j;
        float v;
        if (oc < 128)      v = W[oc * 640 + k];
        else if (oc < 256) v = W[(oc - 128) * 640 + 128 + k]
                             + W[(oc - 128) * 640 + 512 + k];
        else if (oc < 384) v = W[(oc - 256) * 640 + 256 + k];
        else               v = W[(oc - 384) * 640 + 384 + k];
        unsigned short hb = f2bf(v);
        h8[j] = (short)hb;
        l8[j] = (short)f2bf(v - bf2f(hb));
    }
    *(bf16x8*)(Wfh + (size_t)tid * 8) = *(bf16x8*)h8;
    *(bf16x8*)(Wfl + (size_t)tid * 8) = *(bf16x8*)l8;
}

// ---------------------------------------------------------------------------
// Edge binning: meta.x = src*3 + p (direct Y row index), meta.y = dist bits.
// p==3 dropped. deg zeroed first.
// ---------------------------------------------------------------------------
__global__ __launch_bounds__(256) void fill_bucket(const int* __restrict__ src,
                                                   const int* __restrict__ dst,
                                                   const int* __restrict__ pos,
                                                   const float* __restrict__ dist,
                                                   int* __restrict__ deg,
                                                   int2* __restrict__ bucket)
{
    int e = blockIdx.x * 256 + threadIdx.x;
    if (e >= EE) return;
    int p = pos[e];
    if (p == 3) return;
    int d_ = dst[e];
    int slot = atomicAdd(&deg[d_], 1);
    if (slot < CAP)
        bucket[(size_t)d_ * CAP + slot] =
            make_int2(src[e] * 3 + p, __float_as_int(dist[e]));
}

// ---------------------------------------------------------------------------
// Pre-GEMM: M=50k, N=512 virtual cols, K=128. Block = 32 rows x 128 vcols,
// grid (1563, 4). 4 waves, wave w -> vcols by*128 + w*32 .. +31 (one 32x32 acc).
// A-tile: 32 rows x 128 k bf16 in LDS (8 KB), swizzled addr16(s,row)=s*32+(row^s).
// B: direct frag loads from L2-resident Wfh/Wfl (one dwordx4 each).
// Output: by==0 -> base[n][128] f32 (+bias); else Y[n][384] bf16.
// C frag: col=lane&31, row=(reg&3)+8*(reg>>2)+4*(lane>>5).
// ---------------------------------------------------------------------------
__global__ __launch_bounds__(256, 4) void pre_gemm(
    const float* __restrict__ h,
    const unsigned short* __restrict__ Wfh, const unsigned short* __restrict__ Wfl,
    const float* __restrict__ bias,
    float* __restrict__ base, unsigned short* __restrict__ Y)
{
    __shared__ __align__(16) short Af[16 * 32 * 8];   // 8 KB

    const int t = threadIdx.x;
    const int lane = t & 63;
    const int w = t >> 6;
    const int ln = lane & 31;
    const int hs = lane >> 5;
    const int node0 = blockIdx.x * BM;
    const int by = blockIdx.y;

    // ---- stage A: h rows -> Af (f32 -> bf16) ----
    {
        int row = t >> 3;          // 0..31
        int g   = t & 7;           // 16-col group
        int node = node0 + row;
        float ff[16];
        if (node < NN) {
            const float* hp = h + (size_t)node * D + g * 16;
            float4 f0 = *(const float4*)hp;
            float4 f1 = *(const float4*)(hp + 4);
            float4 f2 = *(const float4*)(hp + 8);
            float4 f3 = *(const float4*)(hp + 12);
            ff[0]=f0.x; ff[1]=f0.y; ff[2]=f0.z; ff[3]=f0.w;
            ff[4]=f1.x; ff[5]=f1.y; ff[6]=f1.z; ff[7]=f1.w;
            ff[8]=f2.x; ff[9]=f2.y; ff[10]=f2.z; ff[11]=f2.w;
            ff[12]=f3.x; ff[13]=f3.y; ff[14]=f3.z; ff[15]=f3.w;
        } else {
#pragma unroll
            for (int j = 0; j < 16; ++j) ff[j] = 0.f;
        }
        short b16[16];
#pragma unroll
        for (int j = 0; j < 16; ++j) b16[j] = (short)f2bf(ff[j]);
        int s0 = 2 * g, s1 = 2 * g + 1;
        *(bf16x8*)(Af + (s0 * 32 + (row ^ s0)) * 8) = *(bf16x8*)&b16[0];
        *(bf16x8*)(Af + (s1 * 32 + (row ^ s1)) * 8) = *(bf16x8*)&b16[8];
    }
    __syncthreads();

    const int vcb = by * 4 + w;    // 0..15

    auto LOADB = [&](int s, bf16x8& bh, bf16x8& bl) {
        size_t fo = ((size_t)((vcb * 8 + s) * 2 + hs) * 32 + ln) * 8;
        bh = *(const bf16x8*)(Wfh + fo);
        bl = *(const bf16x8*)(Wfl + fo);
    };
    auto LOADA = [&](int s) -> bf16x8 {
        int sl = s * 2 + hs;
        return *(const bf16x8*)(Af + (sl * 32 + (ln ^ sl)) * 8);
    };

    f32x16 acc;
#pragma unroll
    for (int i = 0; i < 16; ++i) acc[i] = 0.f;

    bf16x8 bh0, bl0, bh1, bl1;
    LOADB(0, bh0, bl0);
#pragma unroll
    for (int s = 0; s < 8; s += 2) {
        if (s + 1 < 8) LOADB(s + 1, bh1, bl1);
        bf16x8 aa = LOADA(s);
        __builtin_amdgcn_s_setprio(1);
        acc = __builtin_amdgcn_mfma_f32_32x32x16_bf16(aa, bh0, acc, 0, 0, 0);
        acc = __builtin_amdgcn_mfma_f32_32x32x16_bf16(aa, bl0, acc, 0, 0, 0);
        __builtin_amdgcn_s_setprio(0);
        if (s + 2 < 8) LOADB(s + 2, bh0, bl0);
        aa = LOADA(s + 1);
        __builtin_amdgcn_s_setprio(1);
        acc = __builtin_amdgcn_mfma_f32_32x32x16_bf16(aa, bh1, acc, 0, 0, 0);
        acc = __builtin_amdgcn_mfma_f32_32x32x16_bf16(aa, bl1, acc, 0, 0, 0);
        __builtin_amdgcn_s_setprio(0);
    }

    // ---- epilogue ----
    int vc = by * 128 + w * 32 + ln;
#pragma unroll
    for (int reg = 0; reg < 16; ++reg) {
        int rl = (reg & 3) + 8 * (reg >> 2) + 4 * hs;
        int grow = node0 + rl;
        if (grow < NN) {
            if (by == 0)
                base[(size_t)grow * D + vc] = acc[reg] + bias[vc];
            else
                Y[(size_t)grow * 384 + (vc - 128)] = f2bf(acc[reg]);
        }
    }
}

// ---------------------------------------------------------------------------
// Aggregate + LayerNorm + ReLU: one wave per node, no LDS, no barriers.
// z[node] = base[node] + sum_e w_e * Y[meta.x]  (meta.x = src*3+p).
// Half-waves process 2 edges/step, 8 steps in flight (16 edges/round);
// lanes >= deg hold zeroed meta -> contribute 0 (no predication needed).
// LN reduce via shfl within 32-lane halves (halves hold identical data
// after the xor-32 combine). Output: half 0 writes float4 per lane.
// ---------------------------------------------------------------------------
__global__ __launch_bounds__(256, 8) void agg_ln(
    const unsigned short* __restrict__ Y, const float* __restrict__ base,
    const int2* __restrict__ bucket, const int* __restrict__ deg,
    const float* __restrict__ gamma, const float* __restrict__ beta,
    float* __restrict__ out)
{
    int w = threadIdx.x >> 6;
    int node = blockIdx.x * 4 + w;
    if (node >= NN) return;
    int lane = threadIdx.x & 63;
    int ln = lane & 31;
    int hs = lane >> 5;

    int n = deg[node];
    if (n > CAP) n = CAP;
    int2 mreg = (lane < n) ? bucket[(size_t)node * CAP + lane] : make_int2(0, 0);

    float a[4] = {0.f, 0.f, 0.f, 0.f};
    for (int b0 = 0; b0 < n; b0 += 16) {       // 16 edges per round
        ushort4 v[8];
        float   wq[8];
#pragma unroll
        for (int j = 0; j < 8; ++j) {
            int idx = b0 + 2 * j + hs;         // <= 63 always
            int s3 = __shfl(mreg.x, idx, 64);  // zeroed lanes -> row 0, w=0
            int wy = __shfl(mreg.y, idx, 64);
            wq[j] = __int_as_float(wy);
            v[j] = *(const ushort4*)(Y + (size_t)s3 * D + ln * 4);
        }
#pragma unroll
        for (int j = 0; j < 8; ++j) {
            a[0] = fmaf(bf2f(v[j].x), wq[j], a[0]);
            a[1] = fmaf(bf2f(v[j].y), wq[j], a[1]);
            a[2] = fmaf(bf2f(v[j].z), wq[j], a[2]);
            a[3] = fmaf(bf2f(v[j].w), wq[j], a[3]);
        }
    }
    // combine half-waves (lane l and l+32 hold the same 4 columns)
#pragma unroll
    for (int c = 0; c < 4; ++c) a[c] += __shfl_xor(a[c], 32, 64);

    float4 bv = *(const float4*)(base + (size_t)node * D + ln * 4);
    float z[4] = {bv.x + a[0], bv.y + a[1], bv.z + a[2], bv.w + a[3]};

    float s = z[0] + z[1] + z[2] + z[3];
    float ss = z[0]*z[0] + z[1]*z[1] + z[2]*z[2] + z[3]*z[3];
#pragma unroll
    for (int m = 1; m < 32; m <<= 1) {         // reduce within 32-lane half
        s  += __shfl_xor(s, m, 64);
        ss += __shfl_xor(ss, m, 64);
    }
    float mu  = s * (1.f / 128.f);
    float var = ss * (1.f / 128.f) - mu * mu;
    float rs  = rsqrtf(var + 1e-5f);

    if (hs == 0) {
        float4 g4 = *(const float4*)(gamma + ln * 4);
        float4 b4 = *(const float4*)(beta + ln * 4);
        float o[4];
        o[0] = (z[0] - mu) * rs * g4.x + b4.x;
        o[1] = (z[1] - mu) * rs * g4.y + b4.y;
        o[2] = (z[2] - mu) * rs * g4.z + b4.z;
        o[3] = (z[3] - mu) * rs * g4.w + b4.w;
#pragma unroll
        for (int c = 0; c < 4; ++c) o[c] = o[c] > 0.f ? o[c] : 0.f;
        *(float4*)(out + (size_t)node * D + ln * 4) = *(float4*)o;
    }
}

// ---------------------------------------------------------------------------
extern "C" void kernel_launch(void* const* d_in, const int* in_sizes, int n_in,
                              void* d_out, int out_size, void* d_ws, size_t ws_size,
                              hipStream_t stream)
{
    const float* h     = (const float*)d_in[0];
    const float* dist  = (const float*)d_in[1];
    const float* W     = (const float*)d_in[2];
    const float* bias  = (const float*)d_in[3];
    const float* gamma = (const float*)d_in[4];
    const float* beta  = (const float*)d_in[5];
    const int*   src   = (const int*)d_in[6];
    const int*   dst   = (const int*)d_in[7];
    const int*   pos   = (const int*)d_in[8];

    // workspace layout
    unsigned short* Wfh  = (unsigned short*)d_ws;           // 128 KB frag-order
    unsigned short* Wfl  = Wfh + 8192 * 8;                  // 128 KB
    unsigned short* Y    = Wfl + 8192 * 8;                  // [NN][384] bf16 38.4MB
    float*          base = (float*)(Y + (size_t)NN * 384);  // [NN][128] f32 25.6MB
    int*            deg  = (int*)(base + (size_t)NN * D);   // [NN]
    int2* bucket = (int2*)(((uintptr_t)(deg + NN) + 15) & ~(uintptr_t)15);

    hipMemsetAsync(deg, 0, NN * sizeof(int), stream);

    prep_wfrag<<<32, 256, 0, stream>>>(W, Wfh, Wfl);
    fill_bucket<<<(EE + 255) / 256, 256, 0, stream>>>(src, dst, pos, dist, deg, bucket);
    pre_gemm<<<dim3(NBX, 4), 256, 0, stream>>>(h, Wfh, Wfl, bias, base, Y);
    agg_ln<<<(NN + 3) / 4, 256, 0, stream>>>(Y, base, bucket, deg, gamma, beta,
                                             (float*)d_out);
}

// Round 10
// 185.783 us; speedup vs baseline: 1.2259x; 1.0275x over previous
//
#include <hip/hip_runtime.h>
#include <math.h>
#include <stdint.h>

constexpr int NN = 50000;   // nodes
constexpr int EE = 800000;  // edges
constexpr int D  = 128;     // feature dim
constexpr int CAP = 64;     // per-node bucket capacity (deg ~ Poisson(12))
constexpr int BM = 32;      // pre-GEMM row tile
constexpr int NBX = (NN + BM - 1) / BM;   // 1563

typedef __attribute__((ext_vector_type(8)))  short bf16x8;
typedef __attribute__((ext_vector_type(16))) float f32x16;

__device__ inline unsigned short f2bf(float x) {
    unsigned u = __builtin_bit_cast(unsigned, x);
    unsigned r = (u + 0x7FFF + ((u >> 16) & 1)) >> 16;   // RNE
    return (unsigned short)r;
}
__device__ inline float bf2f(unsigned short b) {
    unsigned u = ((unsigned)b) << 16;
    return __builtin_bit_cast(float, u);
}

// ---------------------------------------------------------------------------
// W[128][640] -> Wfh/Wfl bf16 hi/lo in MFMA B-fragment order over 512 virtual
// out-cols (vc): vc 0-127 = W0 (h), 128-255 = W1+W4 (p0, t folded),
// 256-383 = W2 (p1), 384-511 = W3 (p2). K = 128 (h dim).
// Wf[(((vcb*8 + s)*2 + hs)*32 + ln)*8 + j] = W_eff[vcb*32+ln][s*16+hs*8+j]
// ---------------------------------------------------------------------------
__global__ __launch_bounds__(256) void prep_wfrag(const float* __restrict__ W,
                                                  unsigned short* __restrict__ Wfh,
                                                  unsigned short* __restrict__ Wfl)
{
    int tid = blockIdx.x * 256 + threadIdx.x;  // 8192 = 16vcb * 8s * 2hs * 32ln
    int ln  = tid & 31;
    int hs  = (tid >> 5) & 1;
    int s   = (tid >> 6) & 7;
    int vcb = tid >> 9;
    int oc  = vcb * 32 + ln;                   // virtual out-col
    short h8[8], l8[8];
#pragma unroll
    for (int j = 0; j < 8; ++j) {
        int k = s * 16 + hs * 8 + j;
        float v;
        if (oc < 128)      v = W[oc * 640 + k];
        else if (oc < 256) v = W[(oc - 128) * 640 + 128 + k]
                             + W[(oc - 128) * 640 + 512 + k];
        else if (oc < 384) v = W[(oc - 256) * 640 + 256 + k];
        else               v = W[(oc - 384) * 640 + 384 + k];
        unsigned short hb = f2bf(v);
        h8[j] = (short)hb;
        l8[j] = (short)f2bf(v - bf2f(hb));
    }
    *(bf16x8*)(Wfh + (size_t)tid * 8) = *(bf16x8*)h8;
    *(bf16x8*)(Wfl + (size_t)tid * 8) = *(bf16x8*)l8;
}

// ---------------------------------------------------------------------------
// Edge binning: meta.x = src*3 + p (direct Y row index), meta.y = dist bits.
// p==3 dropped. deg zeroed first.
// ---------------------------------------------------------------------------
__global__ __launch_bounds__(256) void fill_bucket(const int* __restrict__ src,
                                                   const int* __restrict__ dst,
                                                   const int* __restrict__ pos,
                                                   const float* __restrict__ dist,
                                                   int* __restrict__ deg,
                                                   int2* __restrict__ bucket)
{
    int e = blockIdx.x * 256 + threadIdx.x;
    if (e >= EE) return;
    int p = pos[e];
    if (p == 3) return;
    int d_ = dst[e];
    int slot = atomicAdd(&deg[d_], 1);
    if (slot < CAP)
        bucket[(size_t)d_ * CAP + slot] =
            make_int2(src[e] * 3 + p, __float_as_int(dist[e]));
}

// ---------------------------------------------------------------------------
// Pre-GEMM: M=50k, N=512 virtual cols, K=128. Block = 32 rows x 128 vcols,
// grid (1563, 4). 4 waves, wave w -> vcols by*128 + w*32 .. +31 (one 32x32 acc).
// A-tile: 32 rows x 128 k bf16 in LDS (8 KB), swizzled addr16(s,row)=s*32+(row^s).
// B: direct frag loads from L2-resident Wfh/Wfl (one dwordx4 each).
// Epilogue: C staged bf16 in LDS (reuses A-tile buffer) then COALESCED 16B
// stores. by==0 -> baseB[n][128] bf16 (+bias folded); else Y[(n*3+p)][128] bf16.
// C frag: col=lane&31, row=(reg&3)+8*(reg>>2)+4*(lane>>5).
// ---------------------------------------------------------------------------
__global__ __launch_bounds__(256, 8) void pre_gemm(
    const float* __restrict__ h,
    const unsigned short* __restrict__ Wfh, const unsigned short* __restrict__ Wfl,
    const float* __restrict__ bias,
    unsigned short* __restrict__ baseB, unsigned short* __restrict__ Y)
{
    __shared__ __align__(16) short Af[16 * 32 * 8];   // 8 KB, reused as C-stage

    const int t = threadIdx.x;
    const int lane = t & 63;
    const int w = t >> 6;
    const int ln = lane & 31;
    const int hs = lane >> 5;
    const int node0 = blockIdx.x * BM;
    const int by = blockIdx.y;

    // ---- stage A: h rows -> Af (f32 -> bf16) ----
    {
        int row = t >> 3;          // 0..31
        int g   = t & 7;           // 16-col group
        int node = node0 + row;
        float ff[16];
        if (node < NN) {
            const float* hp = h + (size_t)node * D + g * 16;
            float4 f0 = *(const float4*)hp;
            float4 f1 = *(const float4*)(hp + 4);
            float4 f2 = *(const float4*)(hp + 8);
            float4 f3 = *(const float4*)(hp + 12);
            ff[0]=f0.x; ff[1]=f0.y; ff[2]=f0.z; ff[3]=f0.w;
            ff[4]=f1.x; ff[5]=f1.y; ff[6]=f1.z; ff[7]=f1.w;
            ff[8]=f2.x; ff[9]=f2.y; ff[10]=f2.z; ff[11]=f2.w;
            ff[12]=f3.x; ff[13]=f3.y; ff[14]=f3.z; ff[15]=f3.w;
        } else {
#pragma unroll
            for (int j = 0; j < 16; ++j) ff[j] = 0.f;
        }
        short b16[16];
#pragma unroll
        for (int j = 0; j < 16; ++j) b16[j] = (short)f2bf(ff[j]);
        int s0 = 2 * g, s1 = 2 * g + 1;
        *(bf16x8*)(Af + (s0 * 32 + (row ^ s0)) * 8) = *(bf16x8*)&b16[0];
        *(bf16x8*)(Af + (s1 * 32 + (row ^ s1)) * 8) = *(bf16x8*)&b16[8];
    }
    __syncthreads();

    const int vcb = by * 4 + w;    // 0..15

    auto LOADB = [&](int s, bf16x8& bh, bf16x8& bl) {
        size_t fo = ((size_t)((vcb * 8 + s) * 2 + hs) * 32 + ln) * 8;
        bh = *(const bf16x8*)(Wfh + fo);
        bl = *(const bf16x8*)(Wfl + fo);
    };
    auto LOADA = [&](int s) -> bf16x8 {
        int sl = s * 2 + hs;
        return *(const bf16x8*)(Af + (sl * 32 + (ln ^ sl)) * 8);
    };

    f32x16 acc;
#pragma unroll
    for (int i = 0; i < 16; ++i) acc[i] = 0.f;

    bf16x8 bh0, bl0, bh1, bl1;
    LOADB(0, bh0, bl0);
#pragma unroll
    for (int s = 0; s < 8; s += 2) {
        if (s + 1 < 8) LOADB(s + 1, bh1, bl1);
        bf16x8 aa = LOADA(s);
        __builtin_amdgcn_s_setprio(1);
        acc = __builtin_amdgcn_mfma_f32_32x32x16_bf16(aa, bh0, acc, 0, 0, 0);
        acc = __builtin_amdgcn_mfma_f32_32x32x16_bf16(aa, bl0, acc, 0, 0, 0);
        __builtin_amdgcn_s_setprio(0);
        if (s + 2 < 8) LOADB(s + 2, bh0, bl0);
        aa = LOADA(s + 1);
        __builtin_amdgcn_s_setprio(1);
        acc = __builtin_amdgcn_mfma_f32_32x32x16_bf16(aa, bh1, acc, 0, 0, 0);
        acc = __builtin_amdgcn_mfma_f32_32x32x16_bf16(aa, bl1, acc, 0, 0, 0);
        __builtin_amdgcn_s_setprio(0);
    }
    __syncthreads();               // Af reads done; reuse as C-stage

    // ---- stage C to LDS (bf16), bias folded for by==0 ----
    {
        float bc = (by == 0) ? bias[w * 32 + ln] : 0.f;
        unsigned short* Cs = (unsigned short*)Af;   // [32 row][128 col]
#pragma unroll
        for (int reg = 0; reg < 16; ++reg) {
            int rl = (reg & 3) + 8 * (reg >> 2) + 4 * hs;
            Cs[rl * 128 + w * 32 + ln] = f2bf(acc[reg] + bc);
        }
    }
    __syncthreads();

    // ---- coalesced global stores: 32 rows x 256 B ----
    {
        const unsigned short* Cs = (const unsigned short*)Af;
        int row = t >> 3;          // 0..31
        int g   = t & 7;           // 16-col group
        int grow = node0 + row;
        if (grow < NN) {
            uint2 u0 = *(const uint2*)(Cs + row * 128 + g * 16);
            uint2 u1 = *(const uint2*)(Cs + row * 128 + g * 16 + 4);
            uint2 u2 = *(const uint2*)(Cs + row * 128 + g * 16 + 8);
            uint2 u3 = *(const uint2*)(Cs + row * 128 + g * 16 + 12);
            unsigned short* dp = (by == 0)
                ? baseB + (size_t)grow * D + g * 16
                : Y + ((size_t)grow * 3 + (by - 1)) * D + g * 16;
            *(uint2*)(dp)      = u0;
            *(uint2*)(dp + 4)  = u1;
            *(uint2*)(dp + 8)  = u2;
            *(uint2*)(dp + 12) = u3;
        }
    }
}

// ---------------------------------------------------------------------------
// Aggregate + LayerNorm + ReLU: one wave per node, no LDS, no barriers.
// z[node] = baseB[node] + sum_e w_e * Y[meta.x]  (meta.x = src*3+p).
// Half-waves process 2 edges/step, 8 steps in flight (16 edges/round);
// lanes >= deg hold zeroed meta -> contribute 0.
// ---------------------------------------------------------------------------
__global__ __launch_bounds__(256, 8) void agg_ln(
    const unsigned short* __restrict__ Y, const unsigned short* __restrict__ baseB,
    const int2* __restrict__ bucket, const int* __restrict__ deg,
    const float* __restrict__ gamma, const float* __restrict__ beta,
    float* __restrict__ out)
{
    int w = threadIdx.x >> 6;
    int node = blockIdx.x * 4 + w;
    if (node >= NN) return;
    int lane = threadIdx.x & 63;
    int ln = lane & 31;
    int hs = lane >> 5;

    int n = deg[node];
    if (n > CAP) n = CAP;
    int2 mreg = (lane < n) ? bucket[(size_t)node * CAP + lane] : make_int2(0, 0);

    float a[4] = {0.f, 0.f, 0.f, 0.f};
    for (int b0 = 0; b0 < n; b0 += 16) {       // 16 edges per round
        ushort4 v[8];
        float   wq[8];
#pragma unroll
        for (int j = 0; j < 8; ++j) {
            int idx = b0 + 2 * j + hs;         // <= 63 always
            int s3 = __shfl(mreg.x, idx, 64);  // zeroed lanes -> row 0, w=0
            int wy = __shfl(mreg.y, idx, 64);
            wq[j] = __int_as_float(wy);
            v[j] = *(const ushort4*)(Y + (size_t)s3 * D + ln * 4);
        }
#pragma unroll
        for (int j = 0; j < 8; ++j) {
            a[0] = fmaf(bf2f(v[j].x), wq[j], a[0]);
            a[1] = fmaf(bf2f(v[j].y), wq[j], a[1]);
            a[2] = fmaf(bf2f(v[j].z), wq[j], a[2]);
            a[3] = fmaf(bf2f(v[j].w), wq[j], a[3]);
        }
    }
    // combine half-waves (lane l and l+32 hold the same 4 columns)
#pragma unroll
    for (int c = 0; c < 4; ++c) a[c] += __shfl_xor(a[c], 32, 64);

    ushort4 bv = *(const ushort4*)(baseB + (size_t)node * D + ln * 4);
    float z[4] = {bf2f(bv.x) + a[0], bf2f(bv.y) + a[1],
                  bf2f(bv.z) + a[2], bf2f(bv.w) + a[3]};

    float s = z[0] + z[1] + z[2] + z[3];
    float ss = z[0]*z[0] + z[1]*z[1] + z[2]*z[2] + z[3]*z[3];
#pragma unroll
    for (int m = 1; m < 32; m <<= 1) {         // reduce within 32-lane half
        s  += __shfl_xor(s, m, 64);
        ss += __shfl_xor(ss, m, 64);
    }
    float mu  = s * (1.f / 128.f);
    float var = ss * (1.f / 128.f) - mu * mu;
    float rs  = rsqrtf(var + 1e-5f);

    if (hs == 0) {
        float4 g4 = *(const float4*)(gamma + ln * 4);
        float4 b4 = *(const float4*)(beta + ln * 4);
        float o[4];
        o[0] = (z[0] - mu) * rs * g4.x + b4.x;
        o[1] = (z[1] - mu) * rs * g4.y + b4.y;
        o[2] = (z[2] - mu) * rs * g4.z + b4.z;
        o[3] = (z[3] - mu) * rs * g4.w + b4.w;
#pragma unroll
        for (int c = 0; c < 4; ++c) o[c] = o[c] > 0.f ? o[c] : 0.f;
        *(float4*)(out + (size_t)node * D + ln * 4) = *(float4*)o;
    }
}

// ---------------------------------------------------------------------------
extern "C" void kernel_launch(void* const* d_in, const int* in_sizes, int n_in,
                              void* d_out, int out_size, void* d_ws, size_t ws_size,
                              hipStream_t stream)
{
    const float* h     = (const float*)d_in[0];
    const float* dist  = (const float*)d_in[1];
    const float* W     = (const float*)d_in[2];
    const float* bias  = (const float*)d_in[3];
    const float* gamma = (const float*)d_in[4];
    const float* beta  = (const float*)d_in[5];
    const int*   src   = (const int*)d_in[6];
    const int*   dst   = (const int*)d_in[7];
    const int*   pos   = (const int*)d_in[8];

    // workspace layout
    unsigned short* Wfh   = (unsigned short*)d_ws;            // 128 KB frag-order
    unsigned short* Wfl   = Wfh + 8192 * 8;                   // 128 KB
    unsigned short* Y     = Wfl + 8192 * 8;                   // [NN*3][128] bf16 38.4MB
    unsigned short* baseB = Y + (size_t)NN * 3 * D;           // [NN][128] bf16 12.8MB
    int*            deg   = (int*)(baseB + (size_t)NN * D);   // [NN]
    int2* bucket = (int2*)(((uintptr_t)(deg + NN) + 15) & ~(uintptr_t)15);

    hipMemsetAsync(deg, 0, NN * sizeof(int), stream);

    prep_wfrag<<<32, 256, 0, stream>>>(W, Wfh, Wfl);
    fill_bucket<<<(EE + 255) / 256, 256, 0, stream>>>(src, dst, pos, dist, deg, bucket);
    pre_gemm<<<dim3(NBX, 4), 256, 0, stream>>>(h, Wfh, Wfl, bias, baseB, Y);
    agg_ln<<<(NN + 3) / 4, 256, 0, stream>>>(Y, baseB, bucket, deg, gamma, beta,
                                             (float*)d_out);
}

// Round 11
// 170.775 us; speedup vs baseline: 1.3337x; 1.0879x over previous
//
#include <hip/hip_runtime.h>
#include <math.h>
#include <stdint.h>

constexpr int NN = 50000;   // nodes
constexpr int EE = 800000;  // edges
constexpr int D  = 128;     // feature dim
constexpr int CAP = 64;     // per-node bucket capacity (deg ~ Poisson(12))
constexpr int BM = 32;      // GEMM row tile
constexpr int NBX = (NN + BM - 1) / BM;   // 1563 gemm blocks
constexpr int NBE = (EE + 255) / 256;     // 3125 fill blocks

typedef __attribute__((ext_vector_type(8)))  short bf16x8;
typedef __attribute__((ext_vector_type(16))) float f32x16;

__device__ inline unsigned short f2bf(float x) {
    unsigned u = __builtin_bit_cast(unsigned, x);
    unsigned r = (u + 0x7FFF + ((u >> 16) & 1)) >> 16;   // RNE
    return (unsigned short)r;
}
__device__ inline float bf2f(unsigned short b) {
    unsigned u = ((unsigned)b) << 16;
    return __builtin_bit_cast(float, u);
}

// ---------------------------------------------------------------------------
// W[128][640] -> Wfh/Wfl bf16 hi/lo in MFMA B-fragment order over 512 virtual
// out-cols (vc): 0-127 = W0 (h), 128-255 = W1+W4 (p0, t folded),
// 256-383 = W2 (p1), 384-511 = W3 (p2). K = 128.
// Wf[(((vcb*8 + s)*2 + hs)*32 + ln)*8 + j] = W_eff[vcb*32+ln][s*16+hs*8+j]
// Also zeroes deg[] (so no separate memset dispatch).
// ---------------------------------------------------------------------------
__global__ __launch_bounds__(256) void prep_wfrag(const float* __restrict__ W,
                                                  unsigned short* __restrict__ Wfh,
                                                  unsigned short* __restrict__ Wfl,
                                                  int* __restrict__ deg)
{
    int tid = blockIdx.x * 256 + threadIdx.x;  // 8192 = 16vcb * 8s * 2hs * 32ln
    int ln  = tid & 31;
    int hs  = (tid >> 5) & 1;
    int s   = (tid >> 6) & 7;
    int vcb = tid >> 9;
    int oc  = vcb * 32 + ln;                   // virtual out-col
    short h8[8], l8[8];
#pragma unroll
    for (int j = 0; j < 8; ++j) {
        int k = s * 16 + hs * 8 + j;
        float v;
        if (oc < 128)      v = W[oc * 640 + k];
        else if (oc < 256) v = W[(oc - 128) * 640 + 128 + k]
                             + W[(oc - 128) * 640 + 512 + k];
        else if (oc < 384) v = W[(oc - 256) * 640 + 256 + k];
        else               v = W[(oc - 384) * 640 + 384 + k];
        unsigned short hb = f2bf(v);
        h8[j] = (short)hb;
        l8[j] = (short)f2bf(v - bf2f(hb));
    }
    *(bf16x8*)(Wfh + (size_t)tid * 8) = *(bf16x8*)h8;
    *(bf16x8*)(Wfl + (size_t)tid * 8) = *(bf16x8*)l8;

    for (int i = tid; i < NN; i += 8192) deg[i] = 0;
}

// ---------------------------------------------------------------------------
// MERGED mid kernel. Blocks [0, NBX): pre-GEMM (M=50k, N=512 vcols, K=128) —
// each block does ALL 512 vcols for its 32 rows (h staged ONCE). Blocks
// [NBX, NBX+NBE): edge binning into buckets (meta.x = src*3+p). The two
// paths are independent; concurrent residency hides atomic latency under MFMA.
// GEMM: wave w owns vcb = w*4+q (q=0..3), acc[4] f32x16; 32-step B stream,
// double-buffered direct L2 frag loads; A-tile 8 KB LDS swizzled
// addr16(sl,row)=sl*32+(row^sl). Epilogue: C (32x512 bf16, 32 KB LDS union)
// then fully-coalesced 16B stores: vc<128 -> baseB(+bias), else Y[(n*3+p)].
// C frag: col=lane&31, row=(reg&3)+8*(reg>>2)+4*(lane>>5).
// ---------------------------------------------------------------------------
__global__ __launch_bounds__(256, 2) void fused_mid(
    const float* __restrict__ h,
    const unsigned short* __restrict__ Wfh, const unsigned short* __restrict__ Wfl,
    const float* __restrict__ bias,
    unsigned short* __restrict__ baseB, unsigned short* __restrict__ Y,
    const int* __restrict__ src, const int* __restrict__ dst,
    const int* __restrict__ pos, const float* __restrict__ dist,
    int* __restrict__ deg, int2* __restrict__ bucket)
{
    __shared__ __align__(16) short CsU[32 * 512];   // 32 KB (first 8 KB = A-tile)

    if (blockIdx.x >= NBX) {
        // ---- edge-binning path ----
        int e = (blockIdx.x - NBX) * 256 + threadIdx.x;
        if (e < EE) {
            int p = pos[e];
            if (p != 3) {
                int d_ = dst[e];
                int slot = atomicAdd(&deg[d_], 1);
                if (slot < CAP)
                    bucket[(size_t)d_ * CAP + slot] =
                        make_int2(src[e] * 3 + p, __float_as_int(dist[e]));
            }
        }
        return;
    }

    // ---- GEMM path ----
    short* Af = CsU;                       // 16 slots x 32 rows x 8 bf16
    const int t = threadIdx.x;
    const int lane = t & 63;
    const int w = t >> 6;
    const int ln = lane & 31;
    const int hs = lane >> 5;
    const int node0 = blockIdx.x * BM;

    // stage A: h rows -> Af (f32 -> bf16), once per block
    {
        int row = t >> 3;          // 0..31
        int g   = t & 7;           // 16-col group
        int node = node0 + row;
        float ff[16];
        if (node < NN) {
            const float* hp = h + (size_t)node * D + g * 16;
            float4 f0 = *(const float4*)hp;
            float4 f1 = *(const float4*)(hp + 4);
            float4 f2 = *(const float4*)(hp + 8);
            float4 f3 = *(const float4*)(hp + 12);
            ff[0]=f0.x; ff[1]=f0.y; ff[2]=f0.z; ff[3]=f0.w;
            ff[4]=f1.x; ff[5]=f1.y; ff[6]=f1.z; ff[7]=f1.w;
            ff[8]=f2.x; ff[9]=f2.y; ff[10]=f2.z; ff[11]=f2.w;
            ff[12]=f3.x; ff[13]=f3.y; ff[14]=f3.z; ff[15]=f3.w;
        } else {
#pragma unroll
            for (int j = 0; j < 16; ++j) ff[j] = 0.f;
        }
        short b16[16];
#pragma unroll
        for (int j = 0; j < 16; ++j) b16[j] = (short)f2bf(ff[j]);
        int s0 = 2 * g, s1 = 2 * g + 1;
        *(bf16x8*)(Af + (s0 * 32 + (row ^ s0)) * 8) = *(bf16x8*)&b16[0];
        *(bf16x8*)(Af + (s1 * 32 + (row ^ s1)) * 8) = *(bf16x8*)&b16[8];
    }
    __syncthreads();

    // 32-step fused B stream: step st -> (q = st>>3, s = st&7), vcb = w*4+q
    auto LOADB = [&](int st, bf16x8& bh, bf16x8& bl) {
        int vcb = w * 4 + (st >> 3);
        int s = st & 7;
        size_t fo = ((size_t)((vcb * 8 + s) * 2 + hs) * 32 + ln) * 8;
        bh = *(const bf16x8*)(Wfh + fo);
        bl = *(const bf16x8*)(Wfl + fo);
    };
    auto LOADA = [&](int s) -> bf16x8 {
        int sl = s * 2 + hs;
        return *(const bf16x8*)(Af + (sl * 32 + (ln ^ sl)) * 8);
    };

    f32x16 acc[4];
#pragma unroll
    for (int q = 0; q < 4; ++q)
#pragma unroll
        for (int i = 0; i < 16; ++i) acc[q][i] = 0.f;

    bf16x8 bh0, bl0, bh1, bl1;
    LOADB(0, bh0, bl0);
#pragma unroll
    for (int st = 0; st < 32; st += 2) {
        if (st + 1 < 32) LOADB(st + 1, bh1, bl1);
        bf16x8 aa = LOADA(st & 7);
        __builtin_amdgcn_s_setprio(1);
        acc[st >> 3] = __builtin_amdgcn_mfma_f32_32x32x16_bf16(
            aa, bh0, acc[st >> 3], 0, 0, 0);
        acc[st >> 3] = __builtin_amdgcn_mfma_f32_32x32x16_bf16(
            aa, bl0, acc[st >> 3], 0, 0, 0);
        __builtin_amdgcn_s_setprio(0);
        if (st + 2 < 32) LOADB(st + 2, bh0, bl0);
        aa = LOADA((st + 1) & 7);
        __builtin_amdgcn_s_setprio(1);
        acc[(st + 1) >> 3] = __builtin_amdgcn_mfma_f32_32x32x16_bf16(
            aa, bh1, acc[(st + 1) >> 3], 0, 0, 0);
        acc[(st + 1) >> 3] = __builtin_amdgcn_mfma_f32_32x32x16_bf16(
            aa, bl1, acc[(st + 1) >> 3], 0, 0, 0);
        __builtin_amdgcn_s_setprio(0);
    }
    __syncthreads();               // A reads done; reuse LDS as C-stage

    // stage C: [32 row][512 vc] bf16, bias folded into vc<128 (wave 0)
    {
        unsigned short* Cs = (unsigned short*)CsU;
#pragma unroll
        for (int q = 0; q < 4; ++q) {
            int vc = (w * 4 + q) * 32 + ln;
            float bc = (vc < 128) ? bias[vc] : 0.f;
#pragma unroll
            for (int reg = 0; reg < 16; ++reg) {
                int rl = (reg & 3) + 8 * (reg >> 2) + 4 * hs;
                Cs[rl * 512 + vc] = f2bf(acc[q][reg] + bc);
            }
        }
    }
    __syncthreads();

    // coalesced stores: 2048 16B-chunks, 8 per thread
    {
        const unsigned short* Cs = (const unsigned short*)CsU;
#pragma unroll
        for (int it = 0; it < 8; ++it) {
            int c = t + 256 * it;          // 0..2047
            int row = c >> 6;              // 0..31
            int ci  = c & 63;              // 16B chunk within row
            int vc0 = ci * 8;
            int node = node0 + row;
            if (node < NN) {
                uint2 u0 = *(const uint2*)(Cs + row * 512 + vc0);
                uint2 u1 = *(const uint2*)(Cs + row * 512 + vc0 + 4);
                unsigned short* dp;
                if (vc0 < 128)
                    dp = baseB + (size_t)node * D + vc0;
                else
                    dp = Y + ((size_t)node * 3 + ((vc0 >> 7) - 1)) * D + (vc0 & 127);
                *(uint2*)dp       = u0;
                *(uint2*)(dp + 4) = u1;
            }
        }
    }
}

// ---------------------------------------------------------------------------
// Aggregate + LayerNorm + ReLU: one wave per node, no LDS, no barriers.
// z[node] = baseB[node] + sum_e w_e * Y[meta.x]  (meta.x = src*3+p).
// Half-waves process 2 edges/step, 8 steps in flight; lanes >= deg hold
// zeroed meta -> contribute 0.
// ---------------------------------------------------------------------------
__global__ __launch_bounds__(256, 8) void agg_ln(
    const unsigned short* __restrict__ Y, const unsigned short* __restrict__ baseB,
    const int2* __restrict__ bucket, const int* __restrict__ deg,
    const float* __restrict__ gamma, const float* __restrict__ beta,
    float* __restrict__ out)
{
    int w = threadIdx.x >> 6;
    int node = blockIdx.x * 4 + w;
    if (node >= NN) return;
    int lane = threadIdx.x & 63;
    int ln = lane & 31;
    int hs = lane >> 5;

    int n = deg[node];
    if (n > CAP) n = CAP;
    int2 mreg = (lane < n) ? bucket[(size_t)node * CAP + lane] : make_int2(0, 0);

    float a[4] = {0.f, 0.f, 0.f, 0.f};
    for (int b0 = 0; b0 < n; b0 += 16) {       // 16 edges per round
        ushort4 v[8];
        float   wq[8];
#pragma unroll
        for (int j = 0; j < 8; ++j) {
            int idx = b0 + 2 * j + hs;         // <= 63 always
            int s3 = __shfl(mreg.x, idx, 64);  // zeroed lanes -> row 0, w=0
            int wy = __shfl(mreg.y, idx, 64);
            wq[j] = __int_as_float(wy);
            v[j] = *(const ushort4*)(Y + (size_t)s3 * D + ln * 4);
        }
#pragma unroll
        for (int j = 0; j < 8; ++j) {
            a[0] = fmaf(bf2f(v[j].x), wq[j], a[0]);
            a[1] = fmaf(bf2f(v[j].y), wq[j], a[1]);
            a[2] = fmaf(bf2f(v[j].z), wq[j], a[2]);
            a[3] = fmaf(bf2f(v[j].w), wq[j], a[3]);
        }
    }
    // combine half-waves (lane l and l+32 hold the same 4 columns)
#pragma unroll
    for (int c = 0; c < 4; ++c) a[c] += __shfl_xor(a[c], 32, 64);

    ushort4 bv = *(const ushort4*)(baseB + (size_t)node * D + ln * 4);
    float z[4] = {bf2f(bv.x) + a[0], bf2f(bv.y) + a[1],
                  bf2f(bv.z) + a[2], bf2f(bv.w) + a[3]};

    float s = z[0] + z[1] + z[2] + z[3];
    float ss = z[0]*z[0] + z[1]*z[1] + z[2]*z[2] + z[3]*z[3];
#pragma unroll
    for (int m = 1; m < 32; m <<= 1) {         // reduce within 32-lane half
        s  += __shfl_xor(s, m, 64);
        ss += __shfl_xor(ss, m, 64);
    }
    float mu  = s * (1.f / 128.f);
    float var = ss * (1.f / 128.f) - mu * mu;
    float rs  = rsqrtf(var + 1e-5f);

    if (hs == 0) {
        float4 g4 = *(const float4*)(gamma + ln * 4);
        float4 b4 = *(const float4*)(beta + ln * 4);
        float o[4];
        o[0] = (z[0] - mu) * rs * g4.x + b4.x;
        o[1] = (z[1] - mu) * rs * g4.y + b4.y;
        o[2] = (z[2] - mu) * rs * g4.z + b4.z;
        o[3] = (z[3] - mu) * rs * g4.w + b4.w;
#pragma unroll
        for (int c = 0; c < 4; ++c) o[c] = o[c] > 0.f ? o[c] : 0.f;
        *(float4*)(out + (size_t)node * D + ln * 4) = *(float4*)o;
    }
}

// ---------------------------------------------------------------------------
extern "C" void kernel_launch(void* const* d_in, const int* in_sizes, int n_in,
                              void* d_out, int out_size, void* d_ws, size_t ws_size,
                              hipStream_t stream)
{
    const float* h     = (const float*)d_in[0];
    const float* dist  = (const float*)d_in[1];
    const float* W     = (const float*)d_in[2];
    const float* bias  = (const float*)d_in[3];
    const float* gamma = (const float*)d_in[4];
    const float* beta  = (const float*)d_in[5];
    const int*   src   = (const int*)d_in[6];
    const int*   dst   = (const int*)d_in[7];
    const int*   pos   = (const int*)d_in[8];

    // workspace layout
    unsigned short* Wfh   = (unsigned short*)d_ws;            // 128 KB frag-order
    unsigned short* Wfl   = Wfh + 8192 * 8;                   // 128 KB
    unsigned short* Y     = Wfl + 8192 * 8;                   // [NN*3][128] bf16 38.4MB
    unsigned short* baseB = Y + (size_t)NN * 3 * D;           // [NN][128] bf16 12.8MB
    int*            deg   = (int*)(baseB + (size_t)NN * D);   // [NN]
    int2* bucket = (int2*)(((uintptr_t)(deg + NN) + 15) & ~(uintptr_t)15);

    prep_wfrag<<<32, 256, 0, stream>>>(W, Wfh, Wfl, deg);
    fused_mid<<<NBX + NBE, 256, 0, stream>>>(h, Wfh, Wfl, bias, baseB, Y,
                                             src, dst, pos, dist, deg, bucket);
    agg_ln<<<(NN + 3) / 4, 256, 0, stream>>>(Y, baseB, bucket, deg, gamma, beta,
                                             (float*)d_out);
}